// Round 5
// baseline (280.857 us; speedup 1.0000x reference)
//
#include <hip/hip_runtime.h>

// CCE loss reduction: out[0] = -sum(input * log(target + 1e-8)) / B
// B = 262144, C = 128, f32 inputs. Streaming reduction, memory-bound.
//
// History:
//  R1: grid-stride float4, VGPR=12 -> 2.6 TB/s (latency-bound).
//  R2: 4x batch unroll, VGPR=32, GRID=2048 -> 103 us. Compiler serialized
//      the batch; MLP never materialized.
//  R3: named double-buffer pipeline + sched_barrier, GRID=1024 -> VGPR=48,
//      98 us, 2.74 TB/s. Pipeline real (1 live + 1 in-flight batch).
//  R4: + nontemporal loads + GRID=2048 -> ~82 us (fell below the 77 us
//      poison fills in top-5). TWO variables changed; can't attribute.
//      NEW FACTS: fill WRITE_SIZE at 6.94 TB/s validates TCC byte counters
//      -> R0/R2's FETCH=134 MB vs 268 MB consumed was REAL 50% cache hit.
//      Working set = 268,435,456 B = EXACTLY the 256 MiB Infinity Cache.
//      nt (= L2/L3 evict-first on gfx940+) threw those hits away; the R4
//      win was likely the grid restore DESPITE an nt regression.
//  R5: single-variable A/B — revert nt to plain cached loads, keep
//      GRID=2048 + pipeline. Bench infra failed twice -> no data.
//      This is the R5 retry, byte-identical.
//      Expect FETCH <= 134 MB (hits back) and kernel ~65-72 us if the
//      L3-residency theory holds; ~90+ if nt was the real winner (then
//      the R4 config is final).

typedef float f32x4 __attribute__((ext_vector_type(4)));

constexpr int BLOCK = 256;
constexpr int GRID  = 2048;  // 8 blocks/CU x 256 CUs

__global__ __launch_bounds__(BLOCK, 4) void cce_reduce_kernel(
    const float* __restrict__ inp, const float* __restrict__ tgt,
    float* __restrict__ out, int n4, float neg_inv_b) {
  const f32x4* __restrict__ in4 = reinterpret_cast<const f32x4*>(inp);
  const f32x4* __restrict__ tg4 = reinterpret_cast<const f32x4*>(tgt);

  const int idx    = blockIdx.x * BLOCK + threadIdx.x;
  const int stride = GRID * BLOCK;
  const int step   = 4 * stride;

  // 4 independent accumulator chains.
  float acc0 = 0.f, acc1 = 0.f, acc2 = 0.f, acc3 = 0.f;

#define TERM4(X, Y)                          \
  acc0 += (X)[0] * __logf((Y)[0] + 1e-8f);   \
  acc1 += (X)[1] * __logf((Y)[1] + 1e-8f);   \
  acc2 += (X)[2] * __logf((Y)[2] + 1e-8f);   \
  acc3 += (X)[3] * __logf((Y)[3] + 1e-8f);

  int i = idx;
  if (i + 7 * stride < n4) {  // at least 2 full batches -> pipeline
    // Prologue: batch 0 into the 'a' buffer.
    f32x4 ax0 = in4[i],              ay0 = tg4[i];
    f32x4 ax1 = in4[i + stride],     ay1 = tg4[i + stride];
    f32x4 ax2 = in4[i + 2 * stride], ay2 = tg4[i + 2 * stride];
    f32x4 ax3 = in4[i + 3 * stride], ay3 = tg4[i + 3 * stride];
    i += step;

    // Steady state: issue batch k+1 (8 loads, 8KB/wave) -> compute batch k.
    for (; i + 3 * stride < n4; i += step) {
      f32x4 bx0 = in4[i],              by0 = tg4[i];
      f32x4 bx1 = in4[i + stride],     by1 = tg4[i + stride];
      f32x4 bx2 = in4[i + 2 * stride], by2 = tg4[i + 2 * stride];
      f32x4 bx3 = in4[i + 3 * stride], by3 = tg4[i + 3 * stride];
      // Pin the load cluster: the compiler may not sink loads into the
      // compute to shrink register pressure (R2's failure mode).
      __builtin_amdgcn_sched_barrier(0);

      TERM4(ax0, ay0) TERM4(ax1, ay1) TERM4(ax2, ay2) TERM4(ax3, ay3)

      ax0 = bx0; ay0 = by0; ax1 = bx1; ay1 = by1;
      ax2 = bx2; ay2 = by2; ax3 = bx3; ay3 = by3;
    }
    // Epilogue: compute the last prefetched batch.
    TERM4(ax0, ay0) TERM4(ax1, ay1) TERM4(ax2, ay2) TERM4(ax3, ay3)
  }
  // Generic tail (not taken for 262144x128 with this GRID, but keep general).
  for (; i < n4; i += stride) {
    f32x4 x = in4[i], y = tg4[i];
    TERM4(x, y)
  }
#undef TERM4

  float acc = (acc0 + acc1) + (acc2 + acc3);

  // wave-64 shuffle reduction
  #pragma unroll
  for (int off = 32; off > 0; off >>= 1)
    acc += __shfl_down(acc, off, 64);

  __shared__ float s[BLOCK / 64];
  const int lane = threadIdx.x & 63;
  const int wave = threadIdx.x >> 6;
  if (lane == 0) s[wave] = acc;
  __syncthreads();

  if (threadIdx.x == 0) {
    float t = 0.0f;
    #pragma unroll
    for (int w = 0; w < BLOCK / 64; ++w) t += s[w];
    atomicAdd(out, t * neg_inv_b);  // one device-scope atomic per block
  }
}

extern "C" void kernel_launch(void* const* d_in, const int* in_sizes, int n_in,
                              void* d_out, int out_size, void* d_ws, size_t ws_size,
                              hipStream_t stream) {
  const float* inp = reinterpret_cast<const float*>(d_in[0]);
  const float* tgt = reinterpret_cast<const float*>(d_in[1]);
  float* out = reinterpret_cast<float*>(d_out);

  const long long n = (long long)in_sizes[0];  // 262144 * 128
  const int n4 = (int)(n / 4);                 // exactly divisible (128 cols)
  const long long B = 262144;                  // rows, per reference
  const float neg_inv_b = -1.0f / (float)B;

  // d_out is re-poisoned to 0xAA before every timed launch -> zero it here.
  hipMemsetAsync(d_out, 0, out_size * sizeof(float), stream);

  cce_reduce_kernel<<<GRID, BLOCK, 0, stream>>>(inp, tgt, out, n4, neg_inv_b);
}

// Round 6
// 263.714 us; speedup vs baseline: 1.0650x; 1.0650x over previous
//
#include <hip/hip_runtime.h>

// CCE loss reduction: out[0] = -sum(input * log(target + 1e-8)) / B
// B = 262144, C = 128, f32 inputs. Streaming reduction, memory-bound.
//
// History:
//  R1: grid-stride float4, VGPR=12 -> 2.6 TB/s (latency-bound).
//  R2: 4x batch unroll, VGPR=32, GRID=2048 -> 103 us (compiler serialized).
//  R3: double-buffer pipeline, cached, GRID=1024 -> 98 us, FETCH=134MB.
//  R4: nt loads, GRID=2048 -> ~82 us (3.27 TB/s read-only).
//  R5: cached loads, GRID=2048 -> 113 us, FETCH=134MB (50% L3 hit).
//      VERDICT: nt was the R4 win; cached hits at same request count were
//      SLOWER. At-capacity (256MiB = L3) allocation thrash throttles the
//      read path; nt's no-allocate stream is cheaper per request.
//      Also: R4's 3.27 TB/s == read component of the 6.29 TB/s copy
//      (3.15r+3.15w) while pure-write fill hits 6.94 -> suspect a ~3.3
//      TB/s read-path cap (outstanding-line tracking, ~75 lines/CU).
//  R6 (this): hybrid to distinguish {HBM/latency cap} vs {request-path cap}.
//      target = nt (pure HBM stream, no alloc); input = cached (only
//      128 MiB allocating -> no thrash, becomes L3-resident across the
//      bench's repeat launches).
//      HBM-cap model:    ~55-65 us (L3 hits ride a faster parallel path).
//      request-cap model: ~82-90 us (hit costs a slot like a miss) ->
//      revert to R4 and declare roofline.

typedef float f32x4 __attribute__((ext_vector_type(4)));

constexpr int BLOCK = 256;
constexpr int GRID  = 2048;  // 8 blocks/CU x 256 CUs

__global__ __launch_bounds__(BLOCK, 4) void cce_reduce_kernel(
    const float* __restrict__ inp, const float* __restrict__ tgt,
    float* __restrict__ out, int n4, float neg_inv_b) {
  const f32x4* __restrict__ in4 = reinterpret_cast<const f32x4*>(inp);
  const f32x4* __restrict__ tg4 = reinterpret_cast<const f32x4*>(tgt);

  const int idx    = blockIdx.x * BLOCK + threadIdx.x;
  const int stride = GRID * BLOCK;
  const int step   = 4 * stride;

  // 4 independent accumulator chains.
  float acc0 = 0.f, acc1 = 0.f, acc2 = 0.f, acc3 = 0.f;

  // input: CACHED (128 MiB, L3-resident across launches, no thrash)
  // target: NT (evict-first stream from HBM, no allocation cost)
#define NTL(P) __builtin_nontemporal_load(P)
#define TERM4(X, Y)                          \
  acc0 += (X)[0] * __logf((Y)[0] + 1e-8f);   \
  acc1 += (X)[1] * __logf((Y)[1] + 1e-8f);   \
  acc2 += (X)[2] * __logf((Y)[2] + 1e-8f);   \
  acc3 += (X)[3] * __logf((Y)[3] + 1e-8f);

  int i = idx;
  if (i + 7 * stride < n4) {  // at least 2 full batches -> pipeline
    // Prologue: batch 0 into the 'a' buffer.
    f32x4 ax0 = in4[i],              ay0 = NTL(tg4 + i);
    f32x4 ax1 = in4[i + stride],     ay1 = NTL(tg4 + i + stride);
    f32x4 ax2 = in4[i + 2 * stride], ay2 = NTL(tg4 + i + 2 * stride);
    f32x4 ax3 = in4[i + 3 * stride], ay3 = NTL(tg4 + i + 3 * stride);
    i += step;

    // Steady state: issue batch k+1 (8 loads, 8KB/wave) -> compute batch k.
    for (; i + 3 * stride < n4; i += step) {
      f32x4 bx0 = in4[i],              by0 = NTL(tg4 + i);
      f32x4 bx1 = in4[i + stride],     by1 = NTL(tg4 + i + stride);
      f32x4 bx2 = in4[i + 2 * stride], by2 = NTL(tg4 + i + 2 * stride);
      f32x4 bx3 = in4[i + 3 * stride], by3 = NTL(tg4 + i + 3 * stride);
      // Pin the load cluster: the compiler may not sink loads into the
      // compute to shrink register pressure (R2's failure mode).
      __builtin_amdgcn_sched_barrier(0);

      TERM4(ax0, ay0) TERM4(ax1, ay1) TERM4(ax2, ay2) TERM4(ax3, ay3)

      ax0 = bx0; ay0 = by0; ax1 = bx1; ay1 = by1;
      ax2 = bx2; ay2 = by2; ax3 = bx3; ay3 = by3;
    }
    // Epilogue: compute the last prefetched batch.
    TERM4(ax0, ay0) TERM4(ax1, ay1) TERM4(ax2, ay2) TERM4(ax3, ay3)
  }
  // Generic tail (not taken for 262144x128 with this GRID, but keep general).
  for (; i < n4; i += stride) {
    f32x4 x = in4[i], y = NTL(tg4 + i);
    TERM4(x, y)
  }
#undef TERM4
#undef NTL

  float acc = (acc0 + acc1) + (acc2 + acc3);

  // wave-64 shuffle reduction
  #pragma unroll
  for (int off = 32; off > 0; off >>= 1)
    acc += __shfl_down(acc, off, 64);

  __shared__ float s[BLOCK / 64];
  const int lane = threadIdx.x & 63;
  const int wave = threadIdx.x >> 6;
  if (lane == 0) s[wave] = acc;
  __syncthreads();

  if (threadIdx.x == 0) {
    float t = 0.0f;
    #pragma unroll
    for (int w = 0; w < BLOCK / 64; ++w) t += s[w];
    atomicAdd(out, t * neg_inv_b);  // one device-scope atomic per block
  }
}

extern "C" void kernel_launch(void* const* d_in, const int* in_sizes, int n_in,
                              void* d_out, int out_size, void* d_ws, size_t ws_size,
                              hipStream_t stream) {
  const float* inp = reinterpret_cast<const float*>(d_in[0]);
  const float* tgt = reinterpret_cast<const float*>(d_in[1]);
  float* out = reinterpret_cast<float*>(d_out);

  const long long n = (long long)in_sizes[0];  // 262144 * 128
  const int n4 = (int)(n / 4);                 // exactly divisible (128 cols)
  const long long B = 262144;                  // rows, per reference
  const float neg_inv_b = -1.0f / (float)B;

  // d_out is re-poisoned to 0xAA before every timed launch -> zero it here.
  hipMemsetAsync(d_out, 0, out_size * sizeof(float), stream);

  cce_reduce_kernel<<<GRID, BLOCK, 0, stream>>>(inp, tgt, out, n4, neg_inv_b);
}

// Round 8
// 263.375 us; speedup vs baseline: 1.0664x; 1.0013x over previous
//
#include <hip/hip_runtime.h>

// CCE loss reduction: out[0] = -sum(input * log(target + 1e-8)) / B
// B = 262144, C = 128, f32 inputs. Streaming reduction, memory-bound.
//
// History:
//  R1: grid-stride float4, VGPR=12 -> 2.6 TB/s (latency-bound).
//  R2: 4x batch unroll, VGPR=32, GRID=2048 -> 103 us (compiler serialized).
//  R3: double-buffer pipeline, cached, GRID=1024 -> 98 us, FETCH=134MB.
//  R4: nt loads, GRID=2048 -> ~82 us (3.27 TB/s read-only).
//  R5: cached loads, GRID=2048 -> 113 us, FETCH=134MB. More waves HURT
//      the cached path (R3 98 -> R5 113 at same FETCH).
//  R6: hybrid (input cached / target nt), GRID=2048 -> 78-81 us,
//      FETCH=134MB (input fully L3-resident). 50% L3 hits bought ~3%.
//      MODEL: per-CU outstanding-line cap x latency (Little's law);
//      L3-hit latency ~ HBM latency (memory-side cache), so hit ratio
//      barely matters. Delivered 3.4 TB/s invariant across MLP depth,
//      occupancy, hit ratio, policy. L2 ubench (34.5 TB/s) proves the
//      return path is NOT the cap.
//  R7: wave count at FIXED aggregate outstanding — hybrid policy,
//      GRID=1024 (16 waves/CU), depth-2 pipeline (16 loads, 16KB in
//      flight/wave) -> per-CU demand stays 256KB. Bench infra failed
//      twice -> no data. This is the R7 retry, byte-identical.
//      If R5's fewer-waves win was queue oversubscription: 68-73 us.
//      If invariant (~80 us): the 3.4 TB/s read cap is structural ->
//      declare roofline next round.

typedef float f32x4 __attribute__((ext_vector_type(4)));

constexpr int BLOCK = 256;
constexpr int GRID  = 1024;  // 4 blocks/CU x 256 CUs

__global__ __launch_bounds__(BLOCK, 4) void cce_reduce_kernel(
    const float* __restrict__ inp, const float* __restrict__ tgt,
    float* __restrict__ out, int n4, float neg_inv_b) {
  const f32x4* __restrict__ in4 = reinterpret_cast<const f32x4*>(inp);
  const f32x4* __restrict__ tg4 = reinterpret_cast<const f32x4*>(tgt);

  const int idx    = blockIdx.x * BLOCK + threadIdx.x;
  const int stride = GRID * BLOCK;
  const int step   = 4 * stride;

  // 4 independent accumulator chains.
  float acc0 = 0.f, acc1 = 0.f, acc2 = 0.f, acc3 = 0.f;

  // input: CACHED (128 MiB, L3-resident across launches)
  // target: NT (evict-first stream from HBM, no allocation cost)
#define NTL(P) __builtin_nontemporal_load(P)
#define LOADB(X0, Y0, X1, Y1, X2, Y2, X3, Y3, I)                   \
  X0 = in4[(I)];                Y0 = NTL(tg4 + (I));               \
  X1 = in4[(I) + stride];       Y1 = NTL(tg4 + (I) + stride);      \
  X2 = in4[(I) + 2 * stride];   Y2 = NTL(tg4 + (I) + 2 * stride);  \
  X3 = in4[(I) + 3 * stride];   Y3 = NTL(tg4 + (I) + 3 * stride);
#define TERM4(X, Y)                          \
  acc0 += (X)[0] * __logf((Y)[0] + 1e-8f);   \
  acc1 += (X)[1] * __logf((Y)[1] + 1e-8f);   \
  acc2 += (X)[2] * __logf((Y)[2] + 1e-8f);   \
  acc3 += (X)[3] * __logf((Y)[3] + 1e-8f);
#define COMP(X0, Y0, X1, Y1, X2, Y2, X3, Y3) \
  TERM4(X0, Y0) TERM4(X1, Y1) TERM4(X2, Y2) TERM4(X3, Y3)

  int i = idx;
  if (i + 11 * stride < n4) {  // at least 3 full batches -> depth-2 pipeline
    f32x4 ax0, ay0, ax1, ay1, ax2, ay2, ax3, ay3;   // compute buffer
    f32x4 bx0, by0, bx1, by1, bx2, by2, bx3, by3;   // in flight (k+1)
    f32x4 cx0, cy0, cx1, cy1, cx2, cy2, cx3, cy3;   // in flight (k+2)

    // Prologue: batches 0 and 1 in flight.
    LOADB(ax0, ay0, ax1, ay1, ax2, ay2, ax3, ay3, i)
    LOADB(bx0, by0, bx1, by1, bx2, by2, bx3, by3, i + step)
    i += 2 * step;

    // Steady state: issue batch k+2 (8 loads) -> compute batch k.
    // 16 loads (16KB/wave) stay in flight across the compute.
    for (; i + 3 * stride < n4; i += step) {
      LOADB(cx0, cy0, cx1, cy1, cx2, cy2, cx3, cy3, i)
      // Pin the load cluster: the compiler may not sink loads into the
      // compute to shrink register pressure (R2's failure mode).
      __builtin_amdgcn_sched_barrier(0);

      COMP(ax0, ay0, ax1, ay1, ax2, ay2, ax3, ay3)

      ax0 = bx0; ay0 = by0; ax1 = bx1; ay1 = by1;
      ax2 = bx2; ay2 = by2; ax3 = bx3; ay3 = by3;
      bx0 = cx0; by0 = cy0; bx1 = cx1; by1 = cy1;
      bx2 = cx2; by2 = cy2; bx3 = cx3; by3 = cy3;
    }
    // Epilogue: compute the last two prefetched batches.
    COMP(ax0, ay0, ax1, ay1, ax2, ay2, ax3, ay3)
    COMP(bx0, by0, bx1, by1, bx2, by2, bx3, by3)
  }
  // Generic tail (not taken for 262144x128 with this GRID, but keep general).
  for (; i < n4; i += stride) {
    f32x4 x = in4[i], y = NTL(tg4 + i);
    TERM4(x, y)
  }
#undef COMP
#undef TERM4
#undef LOADB
#undef NTL

  float acc = (acc0 + acc1) + (acc2 + acc3);

  // wave-64 shuffle reduction
  #pragma unroll
  for (int off = 32; off > 0; off >>= 1)
    acc += __shfl_down(acc, off, 64);

  __shared__ float s[BLOCK / 64];
  const int lane = threadIdx.x & 63;
  const int wave = threadIdx.x >> 6;
  if (lane == 0) s[wave] = acc;
  __syncthreads();

  if (threadIdx.x == 0) {
    float t = 0.0f;
    #pragma unroll
    for (int w = 0; w < BLOCK / 64; ++w) t += s[w];
    atomicAdd(out, t * neg_inv_b);  // one device-scope atomic per block
  }
}

extern "C" void kernel_launch(void* const* d_in, const int* in_sizes, int n_in,
                              void* d_out, int out_size, void* d_ws, size_t ws_size,
                              hipStream_t stream) {
  const float* inp = reinterpret_cast<const float*>(d_in[0]);
  const float* tgt = reinterpret_cast<const float*>(d_in[1]);
  float* out = reinterpret_cast<float*>(d_out);

  const long long n = (long long)in_sizes[0];  // 262144 * 128
  const int n4 = (int)(n / 4);                 // exactly divisible (128 cols)
  const long long B = 262144;                  // rows, per reference
  const float neg_inv_b = -1.0f / (float)B;

  // d_out is re-poisoned to 0xAA before every timed launch -> zero it here.
  hipMemsetAsync(d_out, 0, out_size * sizeof(float), stream);

  cce_reduce_kernel<<<GRID, BLOCK, 0, stream>>>(inp, tgt, out, n4, neg_inv_b);
}